// Round 1
// 482.254 us; speedup vs baseline: 1.0311x; 1.0311x over previous
//
#include <hip/hip_runtime.h>
#include <math.h>

#define N_ROWS 262144
#define K_CODES 1024
#define D_DIM 64
#define WL_CAP 262144   // == N_ROWS: overflow (silently-wrong rows) impossible

typedef __attribute__((ext_vector_type(8))) short short8;
typedef __attribute__((ext_vector_type(4))) float f32x4;
typedef unsigned short ushortT;
typedef unsigned int uintT;

// bf16 round-to-nearest-even of a finite fp32, returned as raw bf16 bits.
__device__ inline uintT bf16_rne_bits(float v) {
    uintT u = __float_as_uint(v);
    return (u + 0x7FFFu + ((u >> 16) & 1u)) >> 16;
}

// ---------------------------------------------------------------------------
// Prep: c_sq (EXACT same accumulation order as the validated kernel),
// codebook bf16 hi/lo split, counter zero. Grid widened 4x64CU -> 16 blocks.
// ---------------------------------------------------------------------------
__global__ __launch_bounds__(64) void prep_kernel(const float* __restrict__ cb,
                                                  ushortT* __restrict__ cbh,
                                                  ushortT* __restrict__ cbl,
                                                  float* __restrict__ c_sq,
                                                  int* __restrict__ cnt) {
    if (blockIdx.x == 0 && threadIdx.x == 0) *cnt = 0;
    int k = blockIdx.x * 64 + threadIdx.x;
    if (k >= K_CODES) return;
    const float4* row = (const float4*)(cb + (size_t)k * D_DIM);
    float s = 0.0f;
#pragma unroll
    for (int j = 0; j < D_DIM / 4; ++j) {
        float4 v = row[j];
        s = fmaf(v.x, v.x, s);
        s = fmaf(v.y, v.y, s);
        s = fmaf(v.z, v.z, s);
        s = fmaf(v.w, v.w, s);
        float e[4] = {v.x, v.y, v.z, v.w};
#pragma unroll
        for (int q = 0; q < 4; ++q) {
            int d = 4 * j + q;
            uintT hb = bf16_rne_bits(e[q]);
            float hif = __uint_as_float(hb << 16);
            uintT lb = bf16_rne_bits(e[q] - hif);
            cbh[(size_t)k * D_DIM + d] = (ushortT)hb;
            cbl[(size_t)k * D_DIM + d] = (ushortT)lb;
        }
    }
    c_sq[k] = s;
}

// ---------------------------------------------------------------------------
// Coarse, barrier-free main loop:
//  - B fragments loaded DIRECTLY from global (L1/L2-resident 256 KB split
//    codebook), register double-buffered depth 2. No LDS staging, no
//    per-round __syncthreads, no vmcnt(0) drains.
//  - Tracking of v = 2*dot - c_sq (argmax == argmin distance) in packed
//    sortable ints: low 6 bits = (63 - tl)  (code class n is per-lane
//    constant, so only the tile id needs packing). Truncation error
//    <= 2^-13 for |v| < 16, folded into the gap threshold. Sign-corrupted
//    ordering of negative v is impossible to act on: any row whose merged
//    second-max decodes negative (or x_sq > 170, breaking the |v|<16 bound)
//    is forced to the exact fallback.
//  - x rows staged to LDS at load time (pad 68) so the epilogue residual
//    read does not re-fetch x from HBM.
// ---------------------------------------------------------------------------
__global__ __launch_bounds__(256, 4) void coarse_kernel(
        const float* __restrict__ x_all, const float* __restrict__ cb,
        const ushortT* __restrict__ cbh, const ushortT* __restrict__ cbl,
        const float* __restrict__ c_sq_g,
        float* __restrict__ out_idx, float* __restrict__ out_res,
        float* __restrict__ out_emb, int* __restrict__ cnt,
        int* __restrict__ wl) {
    __shared__ float xs_s[128][68];   // 34816 B, +4 pad floats vs bank stride
    __shared__ float csq_s[K_CODES];  // 4 KB
    __shared__ float xsq_s[128];
    __shared__ int   idx_s[128];

    const int t  = threadIdx.x;
    const int w  = t >> 6;          // wave 0..3
    const int L  = t & 63;          // lane
    const int q  = L >> 4;          // quad 0..3
    const int n  = L & 15;          // class / col
    const int rowbase = blockIdx.x * 128 + w * 32;

    // ---- B fragment bases; issue tiles 0/1 early (in flight during A prep)
    const ushortT* bh_base = cbh + (size_t)n * D_DIM + q * 8;
    const ushortT* bl_base = cbl + (size_t)n * D_DIM + q * 8;
    short8 a_h0 = *(const short8*)(bh_base + 0);
    short8 a_h1 = *(const short8*)(bh_base + 32);
    short8 a_l0 = *(const short8*)(bl_base + 0);
    short8 a_l1 = *(const short8*)(bl_base + 32);
    short8 b_h0 = *(const short8*)(bh_base + 1024);
    short8 b_h1 = *(const short8*)(bh_base + 1024 + 32);
    short8 b_l0 = *(const short8*)(bl_base + 1024);
    short8 b_l1 = *(const short8*)(bl_base + 1024 + 32);

    // ---- c_sq -> LDS (once per block; replaces per-round staging)
    ((float4*)csq_s)[t] = ((const float4*)c_sq_g)[t];

    // ---- load + convert A fragments (x rows), x_sq, stage x rows to LDS
    short8 ah[2][2], al[2][2];
#pragma unroll
    for (int s = 0; s < 2; ++s) {
        float part = 0.0f;
#pragma unroll
        for (int kt = 0; kt < 2; ++kt) {
            const float4* p = (const float4*)(x_all +
                (size_t)(rowbase + s * 16 + n) * D_DIM + kt * 32 + q * 8);
            float4 v0 = p[0], v1 = p[1];
            int lr = w * 32 + s * 16 + n;
            *(float4*)&xs_s[lr][kt * 32 + q * 8] = v0;
            *(float4*)&xs_s[lr][kt * 32 + q * 8 + 4] = v1;
            float e[8] = {v0.x, v0.y, v0.z, v0.w, v1.x, v1.y, v1.z, v1.w};
#pragma unroll
            for (int j = 0; j < 8; ++j) {
                part = fmaf(e[j], e[j], part);
                uintT hb = bf16_rne_bits(e[j]);
                float hif = __uint_as_float(hb << 16);
                uintT lb = bf16_rne_bits(e[j] - hif);
                ah[s][kt][j] = (short)hb;
                al[s][kt][j] = (short)lb;
            }
        }
        part += __shfl_xor(part, 16);
        part += __shfl_xor(part, 32);
        if (q == 0) xsq_s[w * 32 + s * 16 + n] = part;
    }
    __syncthreads();   // csq_s visible (xs_s/xsq_s are wave-private until end)

    // ---- packed trackers: per (rowset s, reg j). INT_MIN = -inf sentinel.
    int m1p[2][4], m2p[2][4];
#pragma unroll
    for (int s = 0; s < 2; ++s)
#pragma unroll
        for (int j = 0; j < 4; ++j) { m1p[s][j] = (int)0x80000000; m2p[s][j] = (int)0x80000000; }

    auto tile_step = [&](int tl, const short8& bh0, const short8& bh1,
                         const short8& bl0, const short8& bl1) {
        f32x4 acc0 = {0.f, 0.f, 0.f, 0.f};
        f32x4 acc1 = {0.f, 0.f, 0.f, 0.f};
        // EXACT same 12-MFMA order as the validated kernel
        acc0 = __builtin_amdgcn_mfma_f32_16x16x32_bf16(ah[0][0], bh0, acc0, 0, 0, 0);
        acc1 = __builtin_amdgcn_mfma_f32_16x16x32_bf16(ah[1][0], bh0, acc1, 0, 0, 0);
        acc0 = __builtin_amdgcn_mfma_f32_16x16x32_bf16(ah[0][1], bh1, acc0, 0, 0, 0);
        acc1 = __builtin_amdgcn_mfma_f32_16x16x32_bf16(ah[1][1], bh1, acc1, 0, 0, 0);
        acc0 = __builtin_amdgcn_mfma_f32_16x16x32_bf16(ah[0][0], bl0, acc0, 0, 0, 0);
        acc1 = __builtin_amdgcn_mfma_f32_16x16x32_bf16(ah[1][0], bl0, acc1, 0, 0, 0);
        acc0 = __builtin_amdgcn_mfma_f32_16x16x32_bf16(ah[0][1], bl1, acc0, 0, 0, 0);
        acc1 = __builtin_amdgcn_mfma_f32_16x16x32_bf16(ah[1][1], bl1, acc1, 0, 0, 0);
        acc0 = __builtin_amdgcn_mfma_f32_16x16x32_bf16(al[0][0], bh0, acc0, 0, 0, 0);
        acc1 = __builtin_amdgcn_mfma_f32_16x16x32_bf16(al[1][0], bh0, acc1, 0, 0, 0);
        acc0 = __builtin_amdgcn_mfma_f32_16x16x32_bf16(al[0][1], bh1, acc0, 0, 0, 0);
        acc1 = __builtin_amdgcn_mfma_f32_16x16x32_bf16(al[1][1], bh1, acc1, 0, 0, 0);

        float cv = csq_s[tl * 16 + n];
        uintT kcp = (uintT)(63 - tl);   // complement -> packed max == first occurrence
#pragma unroll
        for (int j = 0; j < 4; ++j) {
            float v0 = fmaf(2.0f, acc0[j], -cv);
            int u0 = (int)((__float_as_uint(v0) & 0xFFFFFFC0u) | kcp);
            m2p[0][j] = max(m2p[0][j], min(m1p[0][j], u0));
            m1p[0][j] = max(m1p[0][j], u0);
            float v1 = fmaf(2.0f, acc1[j], -cv);
            int u1 = (int)((__float_as_uint(v1) & 0xFFFFFFC0u) | kcp);
            m2p[1][j] = max(m2p[1][j], min(m1p[1][j], u1));
            m1p[1][j] = max(m1p[1][j], u1);
        }
    };

    // ---- main loop: 64 tiles, register double-buffered B, no barriers ----
    for (int tl = 0; tl < 64; tl += 2) {
        tile_step(tl, a_h0, a_h1, a_l0, a_l1);
        if (tl + 2 < 64) {
            size_t o = (size_t)(tl + 2) * 1024;
            a_h0 = *(const short8*)(bh_base + o);
            a_h1 = *(const short8*)(bh_base + o + 32);
            a_l0 = *(const short8*)(bl_base + o);
            a_l1 = *(const short8*)(bl_base + o + 32);
        }
        tile_step(tl + 1, b_h0, b_h1, b_l0, b_l1);
        if (tl + 3 < 64) {
            size_t o = (size_t)(tl + 3) * 1024;
            b_h0 = *(const short8*)(bh_base + o);
            b_h1 = *(const short8*)(bh_base + o + 32);
            b_l0 = *(const short8*)(bl_base + o);
            b_l1 = *(const short8*)(bl_base + o + 32);
        }
    }

    // ---- decode + butterfly reduce across the 16 classes (max-space) ----
#pragma unroll
    for (int s = 0; s < 2; ++s)
#pragma unroll
        for (int j = 0; j < 4; ++j) {
            int p1 = m1p[s][j], p2 = m2p[s][j];
            float a1 = __uint_as_float((uintT)p1 & 0xFFFFFFC0u);
            float a2 = __uint_as_float((uintT)p2 & 0xFFFFFFC0u);
            int ai = ((63 - (p1 & 63)) << 4) | n;   // idx = tl*16 + n
#pragma unroll
            for (int msk = 1; msk < 16; msk <<= 1) {
                float o1 = __shfl_xor(a1, msk);
                float o2 = __shfl_xor(a2, msk);
                int oi = __shfl_xor(ai, msk);
                float nm2 = fmaxf(fminf(a1, o1), fmaxf(a2, o2));
                bool take = (o1 > a1) || (o1 == a1 && oi < ai);
                a1 = take ? o1 : a1;
                ai = take ? oi : ai;
                a2 = nm2;
            }
            if (n == 0) {
                int rl = w * 32 + s * 16 + q * 4 + j;
                float xsq = xsq_s[rl];
                float xn = sqrtf(xsq);
                // 2*margin (validated: 8e-5*xn + 4e-4) + 2*quant (2^-12)
                float thr = fmaf(8.0e-5f, xn, 6.44140625e-4f);
                bool fb = ((a1 - a2) <= thr) || (a2 < 0.0f) || (xsq > 170.0f);
                idx_s[rl] = ai | (fb ? (1 << 30) : 0);
            }
        }
    __syncthreads();

    // ---- outputs ----
    if (t < 128) {
        int e = idx_s[t];
        int row = blockIdx.x * 128 + t;
        out_idx[row] = (float)(e & 0x3FFFFFFF);
        if (e >> 30) {
            int pos = atomicAdd(cnt, 1);
            if (pos < WL_CAP) wl[pos] = row;
        }
    }
    {
        int lr = t >> 1;
        int row = blockIdx.x * 128 + lr;
        int seg = (t & 1) * 32;
        int id = idx_s[lr] & 0x3FFFFFFF;
        const float* xrow = &xs_s[lr][seg];          // exact fp32 x from LDS
        const float4* cs = (const float4*)(cb + (size_t)id * D_DIM + seg);
        float4* rs = (float4*)(out_res + (size_t)row * D_DIM + seg);
        float4* es = (float4*)(out_emb + (size_t)row * D_DIM + seg);
#pragma unroll
        for (int j = 0; j < 8; ++j) {
            float4 xv = *(const float4*)(xrow + 4 * j);
            float4 cv = cs[j];
            float4 rv;
            rv.x = xv.x - cv.x; rv.y = xv.y - cv.y;
            rv.z = xv.z - cv.z; rv.w = xv.w - cv.w;
            rs[j] = rv;
            es[j] = cv;
        }
    }
}

// ---------------------------------------------------------------------------
// Fallback: exact fp32 rescan of worklist rows (unchanged, validated).
// ---------------------------------------------------------------------------
__global__ __launch_bounds__(256) void fallback_kernel(
        const float* __restrict__ x_all, const float* __restrict__ cb,
        const float* __restrict__ c_sq, const int* __restrict__ wl,
        const int* __restrict__ cnt,
        float* __restrict__ out_idx, float* __restrict__ out_res,
        float* __restrict__ out_emb) {
    int count = *cnt;
    if (count > WL_CAP) count = WL_CAP;
    const int L = threadIdx.x & 63;
    const int waveId = blockIdx.x * 4 + (threadIdx.x >> 6);
    const int nWaves = gridDim.x * 4;

    for (int i = waveId; i < count; i += nWaves) {
        int r = wl[i];

        float x[D_DIM];
        const float4* xr = (const float4*)(x_all + (size_t)r * D_DIM);
#pragma unroll
        for (int j = 0; j < D_DIM / 4; ++j) {
            float4 v = xr[j];
            x[4 * j + 0] = v.x; x[4 * j + 1] = v.y;
            x[4 * j + 2] = v.z; x[4 * j + 3] = v.w;
        }
        float x_sq = 0.0f;
#pragma unroll
        for (int d = 0; d < D_DIM; ++d) x_sq = fmaf(x[d], x[d], x_sq);

        float best = INFINITY;
        int bidx = 0x7FFFFFFF;
        for (int kk = 0; kk < 16; ++kk) {
            int k = kk * 64 + L;
            const float* c0 = cb + (size_t)k * D_DIM;
            float a00 = 0.f, a01 = 0.f, a02 = 0.f, a03 = 0.f;
#pragma unroll
            for (int j = 0; j < 4; ++j) {
                float4 v0 = *(const float4*)(c0 + 16 * j + 0);
                float4 v1 = *(const float4*)(c0 + 16 * j + 4);
                float4 v2 = *(const float4*)(c0 + 16 * j + 8);
                float4 v3 = *(const float4*)(c0 + 16 * j + 12);
                float* a = (j == 0) ? &a00 : (j == 1) ? &a01 : (j == 2) ? &a02 : &a03;
                float acc = *a;
                acc = fmaf(x[16 * j + 0],  v0.x, acc);
                acc = fmaf(x[16 * j + 1],  v0.y, acc);
                acc = fmaf(x[16 * j + 2],  v0.z, acc);
                acc = fmaf(x[16 * j + 3],  v0.w, acc);
                acc = fmaf(x[16 * j + 4],  v1.x, acc);
                acc = fmaf(x[16 * j + 5],  v1.y, acc);
                acc = fmaf(x[16 * j + 6],  v1.z, acc);
                acc = fmaf(x[16 * j + 7],  v1.w, acc);
                acc = fmaf(x[16 * j + 8],  v2.x, acc);
                acc = fmaf(x[16 * j + 9],  v2.y, acc);
                acc = fmaf(x[16 * j + 10], v2.z, acc);
                acc = fmaf(x[16 * j + 11], v2.w, acc);
                acc = fmaf(x[16 * j + 12], v3.x, acc);
                acc = fmaf(x[16 * j + 13], v3.y, acc);
                acc = fmaf(x[16 * j + 14], v3.z, acc);
                acc = fmaf(x[16 * j + 15], v3.w, acc);
                *a = acc;
            }
            float dot = (a00 + a01) + (a02 + a03);
            float d = (x_sq - 2.0f * dot) + c_sq[k];
            if (d < best) { best = d; bidx = k; }
        }

#pragma unroll
        for (int msk = 1; msk < 64; msk <<= 1) {
            float ob = __shfl_xor(best, msk);
            int oi = __shfl_xor(bidx, msk);
            bool take = (ob < best) || (ob == best && oi < bidx);
            best = take ? ob : best;
            bidx = take ? oi : bidx;
        }

        if (L < 16) {
            const float4* cbest = (const float4*)(cb + (size_t)bidx * D_DIM);
            float4 c = cbest[L];
            float4 v;
            v.x = x[4 * L + 0] - c.x; v.y = x[4 * L + 1] - c.y;
            v.z = x[4 * L + 2] - c.z; v.w = x[4 * L + 3] - c.w;
            ((float4*)(out_res + (size_t)r * D_DIM))[L] = v;
            ((float4*)(out_emb + (size_t)r * D_DIM))[L] = c;
            if (L == 0) out_idx[r] = (float)bidx;
        }
    }
}

extern "C" void kernel_launch(void* const* d_in, const int* in_sizes, int n_in,
                              void* d_out, int out_size, void* d_ws, size_t ws_size,
                              hipStream_t stream) {
    const float* x  = (const float*)d_in[0];
    const float* cb = (const float*)d_in[1];

    char* base = (char*)d_ws;
    ushortT* cbh = (ushortT*)base;                         // 128 KB
    ushortT* cbl = (ushortT*)(base + 131072);              // 128 KB
    float*   csq = (float*)(base + 262144);                // 4 KB
    int*     cnt = (int*)(base + 266240);
    int*     wl  = (int*)(base + 266256);                  // 1 MB (cap == N)

    float* out   = (float*)d_out;
    float* o_idx = out;
    float* o_res = out + (size_t)N_ROWS;
    float* o_emb = o_res + (size_t)N_ROWS * D_DIM;

    prep_kernel<<<16, 64, 0, stream>>>(cb, cbh, cbl, csq, cnt);
    coarse_kernel<<<N_ROWS / 128, 256, 0, stream>>>(x, cb, cbh, cbl, csq,
                                                    o_idx, o_res, o_emb, cnt, wl);
    fallback_kernel<<<1024, 256, 0, stream>>>(x, cb, csq, wl, cnt,
                                              o_idx, o_res, o_emb);
}